// Round 1
// baseline (3058.008 us; speedup 1.0000x reference)
//
#include <hip/hip_runtime.h>

typedef unsigned short u16;
typedef __attribute__((ext_vector_type(8))) __bf16 bf16x8;
typedef __attribute__((ext_vector_type(4))) float floatx4;

#define NUM_LAYERS 4
#define STEPS 8
#define LRS 0.1f
#define M_ROWS 4096            // B*S
#define D_DIM 1024
#define V_DIM 32000
#define KDIM 1024              // GEMM K
#define NK 16                  // K tiles of 64
#define NTV (V_DIM / 256)      // 125 logits n-tiles
#define SM ((size_t)M_ROWS * D_DIM)
#define WM ((size_t)D_DIM * D_DIM)

__device__ __forceinline__ u16 f2b(float f) {
    union { float f; unsigned u; } c; c.f = f;
    unsigned u = c.u;
    u = (u + 0x7FFFu + ((u >> 16) & 1u)) >> 16;   // RNE
    return (u16)u;
}
__device__ __forceinline__ float b2f(u16 b) {
    union { unsigned u; float f; } c; c.u = ((unsigned)b) << 16;
    return c.f;
}
__device__ __forceinline__ unsigned pk2(float a, float b) {
    return (unsigned)f2b(a) | ((unsigned)f2b(b) << 16);
}

// async 16B global -> LDS (wave-uniform LDS base + lane*16)
__device__ __forceinline__ void ld16(const u16* g, u16* l) {
    __builtin_amdgcn_global_load_lds(
        (const __attribute__((address_space(1))) void*)g,
        (__attribute__((address_space(3))) void*)l, 16, 0, 0);
}

// ---------------------------------------------------------------------------
// 256x256 8-phase GEMM core: C(256x256 f32) = A(256x1024) @ B^T(256x1024), bf16.
// 512 threads = 8 waves (2M x 4N); per-wave 128x64 output = acc[8][4] frags of
// 16x16x32 MFMA. BK=64; LDS = 2 buffers x (A[256][64] + B[256][64]) = 128 KiB.
// Layout: row-major [256][64] u16, k-chunk (8 elems) XOR-swizzled by row&7;
// staging pre-swizzles the GLOBAL source column so global_load_lds stays linear
// (both-sides-or-neither rule). 16-lane-phase bank aliasing is 2-way (free).
// Pipeline (per K-tile t, 4 phases = C-quadrants):
//   P0: ds_read A[m-lo]+B[n-lo]; stage A-half0(t+1) -> buf^1 ; bar;lgkm0;MFMA;bar
//   P1: ds_read B[n-hi];         stage A-half1(t+1) -> buf^1 ; bar;lgkm0;MFMA;bar
//   P2: ds_read A[m-hi];         stage B-half0(t+2) -> buf   ; bar;lgkm0;MFMA;bar
//   P3:                          stage B-half1(t+2) -> buf   ; bar;MFMA;
//       vmcnt(4) (counted -- keeps B(t+2)'s 4 loads in flight across barrier); bar
// Region-safety: every staged region's last ds_read completed before the
// staging wave could pass the preceding barrier (lgkmcnt(0) precedes each
// phase's exit barrier).
// ---------------------------------------------------------------------------
__device__ __forceinline__ void gemm256(const u16* __restrict__ A,
                                        const u16* __restrict__ B,
                                        int m0, int n0,
                                        floatx4 (&acc)[8][4],
                                        u16* __restrict__ smem) {
    const int tid  = threadIdx.x;
    const int lane = tid & 63, wave = tid >> 6;
    const int wm = wave >> 2, wn = wave & 3;
    const int q = lane >> 4, lr = lane & 15;

    // staging map: 512 threads cover 64 rows x 64 k per call (8 lanes/row)
    const int sr = tid >> 3;                       // row within 64-row group
    const int sc = ((tid & 7) ^ (sr & 7)) * 8;     // pre-swizzled global chunk
    const u16* gA = A + (size_t)(m0 + sr) * KDIM + sc;
    const u16* gB = B + (size_t)(n0 + sr) * KDIM + sc;
    const int ldsw = wave * 512;                   // wave's 8-row slice

    // read map
    const int arow = wm * 128 + lr;                // + mi*16
    const int brow = wn * 64 + lr;                 // + ni*16
    const int ck0 = ((q) ^ (lr & 7)) * 8;          // kk=0 swizzled chunk
    const int ck1 = ((4 + q) ^ (lr & 7)) * 8;      // kk=1

    #pragma unroll
    for (int i = 0; i < 8; i++)
        #pragma unroll
        for (int j = 0; j < 4; j++)
            acc[i][j] = floatx4{0.f, 0.f, 0.f, 0.f};

#define STG(bufb, isB, ah, tt) do {                                          \
        const u16* g_ = ((isB) ? gB : gA)                                    \
            + (size_t)((ah) * 128) * KDIM + (size_t)(tt) * 64;               \
        u16* d_ = smem + (bufb) * 32768 + (isB) * 16384 + (ah) * 8192 + ldsw;\
        ld16(g_, d_);                                                        \
        ld16(g_ + (size_t)64 * KDIM, d_ + 4096);                             \
    } while (0)
#define LDA_(mi, ck) (*(const bf16x8*)&smem[bufo + (arow + (mi) * 16) * 64 + (ck)])
#define LDB_(ni, ck) (*(const bf16x8*)&smem[bufo + 16384 + (brow + (ni) * 16) * 64 + (ck)])

    // prologue: tile0 full + B of tile1; keep B(1)'s 4 loads in flight
    STG(0, 0, 0, 0); STG(0, 0, 1, 0);
    STG(0, 1, 0, 0); STG(0, 1, 1, 0);
    STG(1, 1, 0, 1); STG(1, 1, 1, 1);
    asm volatile("s_waitcnt vmcnt(4)" ::: "memory");
    __builtin_amdgcn_s_barrier();
    __builtin_amdgcn_sched_barrier(0);

    bf16x8 af[4][2], bf[4][2];

    #pragma unroll 2
    for (int t = 0; t < NK; ++t) {
        const int bufo = (t & 1) * 32768;
        const int nb = (t + 1) & 1;
        // ---- P0: A m-lo + B n-lo ; stage A-half0(t+1)
        #pragma unroll
        for (int i = 0; i < 4; i++) { af[i][0] = LDA_(i, ck0); af[i][1] = LDA_(i, ck1); }
        #pragma unroll
        for (int j = 0; j < 2; j++) { bf[j][0] = LDB_(j, ck0); bf[j][1] = LDB_(j, ck1); }
        if (t + 1 < NK) STG(nb, 0, 0, t + 1);
        __builtin_amdgcn_s_barrier();
        asm volatile("s_waitcnt lgkmcnt(0)" ::: "memory");
        __builtin_amdgcn_sched_barrier(0);
        __builtin_amdgcn_s_setprio(1);
        #pragma unroll
        for (int i = 0; i < 4; i++)
            #pragma unroll
            for (int j = 0; j < 2; j++) {
                acc[i][j] = __builtin_amdgcn_mfma_f32_16x16x32_bf16(af[i][0], bf[j][0], acc[i][j], 0, 0, 0);
                acc[i][j] = __builtin_amdgcn_mfma_f32_16x16x32_bf16(af[i][1], bf[j][1], acc[i][j], 0, 0, 0);
            }
        __builtin_amdgcn_s_setprio(0);
        __builtin_amdgcn_sched_barrier(0);
        __builtin_amdgcn_s_barrier();
        __builtin_amdgcn_sched_barrier(0);
        // ---- P1: B n-hi ; stage A-half1(t+1)
        #pragma unroll
        for (int j = 2; j < 4; j++) { bf[j][0] = LDB_(j, ck0); bf[j][1] = LDB_(j, ck1); }
        if (t + 1 < NK) STG(nb, 0, 1, t + 1);
        __builtin_amdgcn_s_barrier();
        asm volatile("s_waitcnt lgkmcnt(0)" ::: "memory");
        __builtin_amdgcn_sched_barrier(0);
        __builtin_amdgcn_s_setprio(1);
        #pragma unroll
        for (int i = 0; i < 4; i++)
            #pragma unroll
            for (int j = 2; j < 4; j++) {
                acc[i][j] = __builtin_amdgcn_mfma_f32_16x16x32_bf16(af[i][0], bf[j][0], acc[i][j], 0, 0, 0);
                acc[i][j] = __builtin_amdgcn_mfma_f32_16x16x32_bf16(af[i][1], bf[j][1], acc[i][j], 0, 0, 0);
            }
        __builtin_amdgcn_s_setprio(0);
        __builtin_amdgcn_sched_barrier(0);
        __builtin_amdgcn_s_barrier();
        __builtin_amdgcn_sched_barrier(0);
        // ---- P2: A m-hi ; stage B-half0(t+2)
        #pragma unroll
        for (int i = 0; i < 4; i++) { af[i][0] = LDA_(4 + i, ck0); af[i][1] = LDA_(4 + i, ck1); }
        if (t + 2 < NK) STG(t & 1, 1, 0, t + 2);
        __builtin_amdgcn_s_barrier();
        asm volatile("s_waitcnt lgkmcnt(0)" ::: "memory");
        __builtin_amdgcn_sched_barrier(0);
        __builtin_amdgcn_s_setprio(1);
        #pragma unroll
        for (int i = 0; i < 4; i++)
            #pragma unroll
            for (int j = 0; j < 2; j++) {
                acc[4 + i][j] = __builtin_amdgcn_mfma_f32_16x16x32_bf16(af[i][0], bf[j][0], acc[4 + i][j], 0, 0, 0);
                acc[4 + i][j] = __builtin_amdgcn_mfma_f32_16x16x32_bf16(af[i][1], bf[j][1], acc[4 + i][j], 0, 0, 0);
            }
        __builtin_amdgcn_s_setprio(0);
        __builtin_amdgcn_sched_barrier(0);
        __builtin_amdgcn_s_barrier();
        __builtin_amdgcn_sched_barrier(0);
        // ---- P3: stage B-half1(t+2) ; counted vmcnt
        if (t + 2 < NK) STG(t & 1, 1, 1, t + 2);
        __builtin_amdgcn_s_barrier();
        __builtin_amdgcn_sched_barrier(0);
        __builtin_amdgcn_s_setprio(1);
        #pragma unroll
        for (int i = 0; i < 4; i++)
            #pragma unroll
            for (int j = 2; j < 4; j++) {
                acc[4 + i][j] = __builtin_amdgcn_mfma_f32_16x16x32_bf16(af[i][0], bf[j][0], acc[4 + i][j], 0, 0, 0);
                acc[4 + i][j] = __builtin_amdgcn_mfma_f32_16x16x32_bf16(af[i][1], bf[j][1], acc[4 + i][j], 0, 0, 0);
            }
        __builtin_amdgcn_s_setprio(0);
        __builtin_amdgcn_sched_barrier(0);
        if (t + 2 < NK) { asm volatile("s_waitcnt vmcnt(4)" ::: "memory"); }
        else            { asm volatile("s_waitcnt vmcnt(0)" ::: "memory"); }
        __builtin_amdgcn_s_barrier();
        __builtin_amdgcn_sched_barrier(0);
    }
#undef STG
#undef LDA_
#undef LDB_
}

// f32 epilogue slab: [256][68] (stride 68 breaks banks, keeps 16B alignment)
#define SLAB_S 68

// eps_l = lower - b - mu_l @ W^T. pc_accum==null: write eps bf16; else sum(eps^2).
__global__ __launch_bounds__(512, 2) void eps_gemm_k(
        const u16* __restrict__ sbf, const u16* __restrict__ Wbf,
        const u16* __restrict__ xbf, const float* __restrict__ b_stack,
        u16* __restrict__ epsb, float* __restrict__ pc_accum) {
    __shared__ __align__(16) u16 smem[65536];
    const int z = blockIdx.z;
    const int m0 = blockIdx.y * 256, n0 = blockIdx.x * 256;
    floatx4 acc[8][4];
    gemm256(sbf + (size_t)z * SM, Wbf + (size_t)z * WM, m0, n0, acc, smem);
    const u16* lower = (z == 0) ? xbf : (sbf + (size_t)(z - 1) * SM);
    const float* bias = b_stack + z * D_DIM;
    u16* eo = epsb + (size_t)z * SM;
    const int tid = threadIdx.x, lane = tid & 63, wave = tid >> 6;
    const int wm = wave >> 2, wn = wave & 3, q = lane >> 4, lr = lane & 15;
    float* fp = (float*)smem;
    const int row2 = tid >> 1, scb = (tid & 1) * 32;
    float sq = 0.f;
    #pragma unroll
    for (int ni = 0; ni < 4; ++ni) {
        __syncthreads();
        #pragma unroll
        for (int mi = 0; mi < 8; ++mi)
            #pragma unroll
            for (int r = 0; r < 4; ++r)
                fp[(wm * 128 + mi * 16 + q * 4 + r) * SLAB_S + wn * 16 + lr] = acc[mi][ni][r];
        __syncthreads();
        const int grow = m0 + row2;
        #pragma unroll
        for (int j = 0; j < 8; ++j) {
            const int sc_ = scb + j * 4;
            float4 v = *(const float4*)&fp[row2 * SLAB_S + sc_];
            const int gcol = n0 + (sc_ >> 4) * 64 + ni * 16 + (sc_ & 15);
            const size_t gidx = (size_t)grow * D_DIM + gcol;
            const float4 b4 = *(const float4*)&bias[gcol];
            ushort4 lo4 = *(const ushort4*)(lower + gidx);
            float e0 = b2f(lo4.x) - (v.x + b4.x);
            float e1 = b2f(lo4.y) - (v.y + b4.y);
            float e2 = b2f(lo4.z) - (v.z + b4.z);
            float e3 = b2f(lo4.w) - (v.w + b4.w);
            if (pc_accum) {
                sq += e0 * e0 + e1 * e1 + e2 * e2 + e3 * e3;
            } else {
                uint2 ov; ov.x = pk2(e0, e1); ov.y = pk2(e2, e3);
                *(uint2*)(eo + gidx) = ov;
            }
        }
    }
    if (pc_accum) {
        #pragma unroll
        for (int off = 1; off < 64; off <<= 1) sq += __shfl_xor(sq, off, 64);
        __syncthreads();
        if (lane == 0) fp[wave] = sq;
        __syncthreads();
        if (tid == 0) {
            float s = 0.f;
            #pragma unroll
            for (int w = 0; w < 8; ++w) s += fp[w];
            atomicAdd(pc_accum, s);
        }
    }
}

// s_l += LR*(eps_l @ W) - LR*eps_{l+1}
__global__ __launch_bounds__(512, 2) void upd_gemm_k(
        const u16* __restrict__ epsb, const u16* __restrict__ WTbf,
        u16* __restrict__ sbf) {
    __shared__ __align__(16) u16 smem[65536];
    const int z = blockIdx.z;
    const int m0 = blockIdx.y * 256, n0 = blockIdx.x * 256;
    floatx4 acc[8][4];
    gemm256(epsb + (size_t)z * SM, WTbf + (size_t)z * WM, m0, n0, acc, smem);
    u16* Sb = sbf + (size_t)z * SM;
    const bool hn = (z < 3);
    const u16* en = epsb + (size_t)(hn ? (z + 1) : z) * SM;
    const int tid = threadIdx.x, lane = tid & 63, wave = tid >> 6;
    const int wm = wave >> 2, wn = wave & 3, q = lane >> 4, lr = lane & 15;
    float* fp = (float*)smem;
    const int row2 = tid >> 1, scb = (tid & 1) * 32;
    #pragma unroll
    for (int ni = 0; ni < 4; ++ni) {
        __syncthreads();
        #pragma unroll
        for (int mi = 0; mi < 8; ++mi)
            #pragma unroll
            for (int r = 0; r < 4; ++r)
                fp[(wm * 128 + mi * 16 + q * 4 + r) * SLAB_S + wn * 16 + lr] = acc[mi][ni][r];
        __syncthreads();
        const int grow = m0 + row2;
        #pragma unroll
        for (int j = 0; j < 8; ++j) {
            const int sc_ = scb + j * 4;
            float4 v = *(const float4*)&fp[row2 * SLAB_S + sc_];
            const int gcol = n0 + (sc_ >> 4) * 64 + ni * 16 + (sc_ & 15);
            const size_t gidx = (size_t)grow * D_DIM + gcol;
            ushort4 S8 = *(const ushort4*)(Sb + gidx);
            float v0 = b2f(S8.x) + LRS * v.x;
            float v1 = b2f(S8.y) + LRS * v.y;
            float v2 = b2f(S8.z) + LRS * v.z;
            float v3 = b2f(S8.w) + LRS * v.w;
            if (hn) {
                ushort4 e8 = *(const ushort4*)(en + gidx);
                v0 -= LRS * b2f(e8.x); v1 -= LRS * b2f(e8.y);
                v2 -= LRS * b2f(e8.z); v3 -= LRS * b2f(e8.w);
            }
            uint2 ov; ov.x = pk2(v0, v1); ov.y = pk2(v2, v3);
            *(uint2*)(Sb + gidx) = ov;
        }
    }
}

// logits tile + fused online-softmax partials + target-logit capture
// grid: x = m-tile (fastest) so co-resident blocks share one B n-strip
__global__ __launch_bounds__(512, 2) void logits_k(
        const u16* __restrict__ s4bf, const u16* __restrict__ oWb,
        const float* __restrict__ out_b, const int* __restrict__ targets,
        float* __restrict__ part_m, float* __restrict__ part_s,
        float* __restrict__ tlog) {
    __shared__ __align__(16) u16 smem[65536];
    const int m0 = blockIdx.x * 256, n0 = blockIdx.y * 256;
    floatx4 acc[8][4];
    gemm256(s4bf, oWb, m0, n0, acc, smem);
    const int tid = threadIdx.x, lane = tid & 63, wave = tid >> 6;
    const int wm = wave >> 2, wn = wave & 3, q = lane >> 4, lr = lane & 15;
    float* redm = (float*)smem;        // [256][4]
    float* reds = redm + 1024;
    float ob[4];
    #pragma unroll
    for (int ni = 0; ni < 4; ++ni) ob[ni] = out_b[n0 + wn * 64 + ni * 16 + lr];
    __syncthreads();
    #pragma unroll
    for (int mi = 0; mi < 8; ++mi) {
        #pragma unroll
        for (int r = 0; r < 4; ++r) {
            const int rrow = wm * 128 + mi * 16 + q * 4 + r;
            const int grow = m0 + rrow;
            float l[4];
            #pragma unroll
            for (int ni = 0; ni < 4; ni++) l[ni] = acc[mi][ni][r] + ob[ni];
            if ((grow & 511) != 511) {             // valid row (s < 511)
                const int tg = targets[grow + 1];
                #pragma unroll
                for (int ni = 0; ni < 4; ni++) {
                    const int gcol = n0 + wn * 64 + ni * 16 + lr;
                    if (tg == gcol) tlog[grow] = l[ni];
                }
            }
            float mx = fmaxf(fmaxf(l[0], l[1]), fmaxf(l[2], l[3]));
            #pragma unroll
            for (int off = 1; off < 16; off <<= 1)
                mx = fmaxf(mx, __shfl_xor(mx, off, 64));
            float sm = __expf(l[0] - mx) + __expf(l[1] - mx) +
                       __expf(l[2] - mx) + __expf(l[3] - mx);
            #pragma unroll
            for (int off = 1; off < 16; off <<= 1)
                sm += __shfl_xor(sm, off, 64);
            if (lr == 0) { redm[rrow * 4 + wn] = mx; reds[rrow * 4 + wn] = sm; }
        }
    }
    __syncthreads();
    if (tid < 256) {
        float ma = redm[tid * 4], mb = redm[tid * 4 + 1];
        float mc = redm[tid * 4 + 2], md = redm[tid * 4 + 3];
        float M = fmaxf(fmaxf(ma, mb), fmaxf(mc, md));
        float S = reds[tid * 4] * __expf(ma - M) + reds[tid * 4 + 1] * __expf(mb - M)
                + reds[tid * 4 + 2] * __expf(mc - M) + reds[tid * 4 + 3] * __expf(md - M);
        part_m[(size_t)blockIdx.y * M_ROWS + m0 + tid] = M;
        part_s[(size_t)blockIdx.y * M_ROWS + m0 + tid] = S;
    }
}

__global__ void gather_k(const int* __restrict__ ids,
                         const float* __restrict__ emb,
                         u16* __restrict__ xbf) {
    const int row = blockIdx.x;
    const int c = threadIdx.x * 4;
    float4 v = *(const float4*)(emb + (size_t)ids[row] * D_DIM + c);
    uint2 o; o.x = pk2(v.x, v.y); o.y = pk2(v.z, v.w);
    *(uint2*)(xbf + (size_t)row * D_DIM + c) = o;
}

__global__ void conv_w_k(const float* __restrict__ W,
                         u16* __restrict__ Wbf, u16* __restrict__ WTbf) {
    __shared__ float t[32][33];
    const int z = blockIdx.z;
    const int i = blockIdx.y * 32 + threadIdx.y;
    const int j = blockIdx.x * 32 + threadIdx.x;
    const float v = W[(size_t)z * WM + (size_t)i * D_DIM + j];
    Wbf[(size_t)z * WM + (size_t)i * D_DIM + j] = f2b(v);
    t[threadIdx.y][threadIdx.x] = v;
    __syncthreads();
    const int jo = blockIdx.x * 32 + threadIdx.y;
    const int io = blockIdx.y * 32 + threadIdx.x;
    WTbf[(size_t)z * WM + (size_t)jo * D_DIM + io] = f2b(t[threadIdx.x][threadIdx.y]);
}

__global__ void conv_outw_k(const float* __restrict__ oW, u16* __restrict__ oWb) {
    const size_t i = ((size_t)blockIdx.x * 256 + threadIdx.x) * 4;
    float4 v = *(const float4*)(oW + i);
    uint2 o; o.x = pk2(v.x, v.y); o.y = pk2(v.z, v.w);
    *(uint2*)(oWb + i) = o;
}

__global__ void init_states_k(const float* __restrict__ si,
                              u16* __restrict__ sbf) {
    const size_t i = ((size_t)blockIdx.x * 256 + threadIdx.x) * 4;
    float4 v = *(const float4*)(si + i);
    uint2 o; o.x = pk2(v.x, v.y); o.y = pk2(v.z, v.w);
    *(uint2*)(sbf + i) = o;
}

__global__ void ce_reduce_k(const float* __restrict__ part_m,
                            const float* __restrict__ part_s,
                            const float* __restrict__ tlog,
                            float* __restrict__ ce_sum) {
    const int row = blockIdx.x;
    if ((row & 511) == 511) return;
    const int tid = threadIdx.x;
    const int NT = NTV;  // 125
    float m = -3.0e38f;
    for (int nt = tid; nt < NT; nt += 256)
        m = fmaxf(m, part_m[(size_t)nt * M_ROWS + row]);
    #pragma unroll
    for (int off = 1; off < 64; off <<= 1) m = fmaxf(m, __shfl_xor(m, off, 64));
    __shared__ float sm[4], ss[4];
    if ((tid & 63) == 0) sm[tid >> 6] = m;
    __syncthreads();
    m = fmaxf(fmaxf(sm[0], sm[1]), fmaxf(sm[2], sm[3]));
    float s = 0.f;
    for (int nt = tid; nt < NT; nt += 256)
        s += part_s[(size_t)nt * M_ROWS + row] *
             __expf(part_m[(size_t)nt * M_ROWS + row] - m);
    #pragma unroll
    for (int off = 1; off < 64; off <<= 1) s += __shfl_xor(s, off, 64);
    if ((tid & 63) == 0) ss[tid >> 6] = s;
    __syncthreads();
    if (tid == 0) {
        float loss = m + __logf(ss[0] + ss[1] + ss[2] + ss[3]) - tlog[row];
        atomicAdd(ce_sum, loss);
    }
}

__global__ void finalize_k(const float* __restrict__ scal, float* __restrict__ out) {
    out[0] = scal[0] / 4088.0f;
    out[1] = scal[1] / (float)(4 * SM);
}

extern "C" void kernel_launch(void* const* d_in, const int* in_sizes, int n_in,
                              void* d_out, int out_size, void* d_ws, size_t ws_size,
                              hipStream_t stream) {
    (void)in_sizes; (void)n_in; (void)out_size; (void)ws_size;
    const int*   ids = (const int*)d_in[0];
    const int*   tgt = (const int*)d_in[1];
    const float* emb = (const float*)d_in[2];
    const float* W   = (const float*)d_in[3];
    const float* bs  = (const float*)d_in[4];
    const float* oW  = (const float*)d_in[5];
    const float* ob  = (const float*)d_in[6];
    const float* si  = (const float*)d_in[7];

    char* ws = (char*)d_ws;
    u16*   sbf    = (u16*)  (ws + 0);             // 33,554,432 B
    u16*   epsb   = (u16*)  (ws + 33554432);      // 33,554,432 B
    u16*   xbf    = (u16*)  (ws + 67108864);      //  8,388,608 B
    u16*   Wbf    = (u16*)  (ws + 75497472);      //  8,388,608 B
    u16*   WTbf   = (u16*)  (ws + 83886080);      //  8,388,608 B
    u16*   oWb    = (u16*)  (ws + 92274688);      // 65,536,000 B
    float* part_m = (float*)(ws + 157810688);     //  4,096,000 B (125 used)
    float* part_s = (float*)(ws + 161906688);     //  4,096,000 B
    float* tlog   = (float*)(ws + 166002688);     //     16,384 B
    float* scal   = (float*)(ws + 166019072);     //        256 B

    hipMemsetAsync(scal, 0, 256, stream);
    gather_k<<<M_ROWS, 256, 0, stream>>>(ids, emb, xbf);
    conv_w_k<<<dim3(32, 32, 4), dim3(32, 32), 0, stream>>>(W, Wbf, WTbf);
    conv_outw_k<<<(V_DIM * D_DIM) / 1024, 256, 0, stream>>>(oW, oWb);
    init_states_k<<<(4 * (int)SM) / 1024, 256, 0, stream>>>(si, sbf);

    for (int step = 0; step < STEPS; ++step) {
        eps_gemm_k<<<dim3(4, 16, 4), 512, 0, stream>>>(sbf, Wbf, xbf, bs, epsb,
                                                       nullptr);
        upd_gemm_k<<<dim3(4, 16, 4), 512, 0, stream>>>(epsb, WTbf, sbf);
    }
    // final eps pass: no eps write, accumulate sum(eps^2) directly
    eps_gemm_k<<<dim3(4, 16, 4), 512, 0, stream>>>(sbf, Wbf, xbf, bs, epsb,
                                                   scal + 1);
    logits_k<<<dim3(16, NTV), 512, 0, stream>>>(sbf + 3 * SM, oWb, ob, tgt,
                                                part_m, part_s, tlog);
    ce_reduce_k<<<M_ROWS, 256, 0, stream>>>(part_m, part_s, tlog, scal);
    finalize_k<<<1, 1, 0, stream>>>(scal, (float*)d_out);
}

// Round 2
// 1585.211 us; speedup vs baseline: 1.9291x; 1.9291x over previous
//
#include <hip/hip_runtime.h>

typedef unsigned short u16;
typedef __attribute__((ext_vector_type(8))) __bf16 bf16x8;
typedef __attribute__((ext_vector_type(4))) float floatx4;

#define NUM_LAYERS 4
#define STEPS 8
#define LRS 0.1f
#define M_ROWS 4096            // B*S
#define D_DIM 1024
#define V_DIM 32000
#define KDIM 1024              // GEMM K
#define NK 16                  // K tiles of 64 (256-tile core)
#define NTV (V_DIM / 256)      // 125 logits n-tiles
#define SM ((size_t)M_ROWS * D_DIM)
#define WM ((size_t)D_DIM * D_DIM)

__device__ __forceinline__ u16 f2b(float f) {
    union { float f; unsigned u; } c; c.f = f;
    unsigned u = c.u;
    u = (u + 0x7FFFu + ((u >> 16) & 1u)) >> 16;   // RNE
    return (u16)u;
}
__device__ __forceinline__ float b2f(u16 b) {
    union { unsigned u; float f; } c; c.u = ((unsigned)b) << 16;
    return c.f;
}
__device__ __forceinline__ unsigned pk2(float a, float b) {
    return (unsigned)f2b(a) | ((unsigned)f2b(b) << 16);
}

// async 16B global -> LDS (wave-uniform LDS base + lane*16)
__device__ __forceinline__ void ld16(const u16* g, u16* l) {
    __builtin_amdgcn_global_load_lds(
        (const __attribute__((address_space(1))) void*)g,
        (__attribute__((address_space(3))) void*)l, 16, 0, 0);
}

// ---------------------------------------------------------------------------
// 128x128 2-phase GEMM core (round-0 verified, ~850 TF structure ceiling).
// 256 threads = 4 waves in 2x2; each wave 64x64 = 4x4 frags of 16x16x32 MFMA.
// Used for eps/upd (4 blocks/CU co-residency hides the barrier drains).
// smem: caller-provided 16384 u16 (A halves [0,8192), B halves [8192,16384)).
// ---------------------------------------------------------------------------
__device__ __forceinline__ void gemm_core(const u16* __restrict__ A,
                                          const u16* __restrict__ B,
                                          int m0, int n0,
                                          floatx4 (&acc)[4][4],
                                          u16* smem) {
    u16* a_lds = smem;           // [2][4096] halves
    u16* b_lds = smem + 8192;
    const int tid  = threadIdx.x;
    const int lane = tid & 63;
    const int wave = tid >> 6;
    const int wm = wave >> 1, wn = wave & 1;
    const int q = lane >> 4, lr = lane & 15;
    const int qs = q ^ ((lr >> 1) & 3);          // read-side swizzle

    const int r0 = wave * 16 + (lane >> 2);
    const int cc = ((lane & 3) ^ ((lane >> 3) & 3)) * 8;
    const u16* ga = A + ((size_t)(m0 + r0) << 10) + cc;   // row stride 1024
    const u16* gb = B + ((size_t)(n0 + r0) << 10) + cc;
    u16* la = &a_lds[wave * 512];
    u16* lb = &b_lds[wave * 512];

    #pragma unroll
    for (int i = 0; i < 4; i++)
        #pragma unroll
        for (int j = 0; j < 4; j++)
            acc[i][j] = floatx4{0.f, 0.f, 0.f, 0.f};

    for (int kt = 0; kt < KDIM; kt += 64) {
        __syncthreads();                 // previous iter's LDS reads done
        ld16(ga + kt,                   la);
        ld16(ga + kt + 32,              la + 4096);
        ld16(ga + (64 << 10) + kt,      la + 2048);
        ld16(ga + (64 << 10) + kt + 32, la + 2048 + 4096);
        ld16(gb + kt,                   lb);
        ld16(gb + kt + 32,              lb + 4096);
        ld16(gb + (64 << 10) + kt,      lb + 2048);
        ld16(gb + (64 << 10) + kt + 32, lb + 2048 + 4096);
        __syncthreads();                 // drains vmcnt before reads
        #pragma unroll
        for (int h = 0; h < 2; h++) {
            bf16x8 bfv[4];
            #pragma unroll
            for (int ni = 0; ni < 4; ni++)
                bfv[ni] = *(const bf16x8*)
                    &b_lds[h * 4096 + (wn * 64 + ni * 16 + lr) * 32 + qs * 8];
            #pragma unroll
            for (int mi = 0; mi < 4; mi++) {
                bf16x8 a = *(const bf16x8*)
                    &a_lds[h * 4096 + (wm * 64 + mi * 16 + lr) * 32 + qs * 8];
                #pragma unroll
                for (int ni = 0; ni < 4; ni++)
                    acc[mi][ni] = __builtin_amdgcn_mfma_f32_16x16x32_bf16(
                        a, bfv[ni], acc[mi][ni], 0, 0, 0);
            }
        }
    }
}

// ---------------------------------------------------------------------------
// 256x256 8-phase GEMM core (for logits_k). De-pinned vs round 1: NO
// sched_barrier(0), NO inline lgkmcnt (compiler tracks af/bf deps itself);
// keep barrier skeleton + counted vmcnt (memory-clobbered asm = the only
// ordering fence staging safety needs) + setprio around MFMA clusters.
// 512 threads = 8 waves (2M x 4N); per-wave 128x64 = acc[8][4]. BK=64,
// LDS = 2 x (A[256][64] + B[256][64]) = 128 KiB, chunk-XOR swizzle (row&7)
// applied on pre-swizzled global source + read side (conflict-free, r1 PMC).
// ---------------------------------------------------------------------------
__device__ __forceinline__ void gemm256(const u16* __restrict__ A,
                                        const u16* __restrict__ B,
                                        int m0, int n0,
                                        floatx4 (&acc)[8][4],
                                        u16* __restrict__ smem) {
    const int tid  = threadIdx.x;
    const int lane = tid & 63, wave = tid >> 6;
    const int wm = wave >> 2, wn = wave & 3;
    const int q = lane >> 4, lr = lane & 15;

    // staging map: 512 threads cover 128 rows x 64 k per STG (2 ld16 each)
    const int sr = tid >> 3;                       // row within 64-row group
    const int sc = ((tid & 7) ^ (sr & 7)) * 8;     // pre-swizzled global chunk
    const u16* gA = A + (size_t)(m0 + sr) * KDIM + sc;
    const u16* gB = B + (size_t)(n0 + sr) * KDIM + sc;
    const int ldsw = wave * 512;                   // wave's 8-row slice

    // read map
    const int arow = wm * 128 + lr;                // + mi*16
    const int brow = wn * 64 + lr;                 // + ni*16
    const int ck0 = ((q) ^ (lr & 7)) * 8;          // kk=0 swizzled chunk
    const int ck1 = ((4 + q) ^ (lr & 7)) * 8;      // kk=1

    #pragma unroll
    for (int i = 0; i < 8; i++)
        #pragma unroll
        for (int j = 0; j < 4; j++)
            acc[i][j] = floatx4{0.f, 0.f, 0.f, 0.f};

#define STG(bufb, isB, ah, tt) do {                                          \
        const u16* g_ = ((isB) ? gB : gA)                                    \
            + (size_t)((ah) * 128) * KDIM + (size_t)(tt) * 64;               \
        u16* d_ = smem + (bufb) * 32768 + (isB) * 16384 + (ah) * 8192 + ldsw;\
        ld16(g_, d_);                                                        \
        ld16(g_ + (size_t)64 * KDIM, d_ + 4096);                             \
    } while (0)
#define LDA_(mi, ck) (*(const bf16x8*)&smem[bufo + (arow + (mi) * 16) * 64 + (ck)])
#define LDB_(ni, ck) (*(const bf16x8*)&smem[bufo + 16384 + (brow + (ni) * 16) * 64 + (ck)])

    // prologue: tile0 full + B of tile1; keep B(1)'s 4 loads in flight
    STG(0, 0, 0, 0); STG(0, 0, 1, 0);
    STG(0, 1, 0, 0); STG(0, 1, 1, 0);
    STG(1, 1, 0, 1); STG(1, 1, 1, 1);
    asm volatile("s_waitcnt vmcnt(4)" ::: "memory");
    __builtin_amdgcn_s_barrier();

    bf16x8 af[4][2], bf[4][2];

    #pragma unroll 2
    for (int t = 0; t < NK; ++t) {
        const int bufo = (t & 1) * 32768;
        const int nb = (t + 1) & 1;
        // ---- P0: read A m-lo + B n-lo ; stage A-half0(t+1)
        #pragma unroll
        for (int i = 0; i < 4; i++) { af[i][0] = LDA_(i, ck0); af[i][1] = LDA_(i, ck1); }
        #pragma unroll
        for (int j = 0; j < 2; j++) { bf[j][0] = LDB_(j, ck0); bf[j][1] = LDB_(j, ck1); }
        if (t + 1 < NK) STG(nb, 0, 0, t + 1);
        __builtin_amdgcn_s_barrier();
        __builtin_amdgcn_s_setprio(1);
        #pragma unroll
        for (int i = 0; i < 4; i++)
            #pragma unroll
            for (int j = 0; j < 2; j++) {
                acc[i][j] = __builtin_amdgcn_mfma_f32_16x16x32_bf16(af[i][0], bf[j][0], acc[i][j], 0, 0, 0);
                acc[i][j] = __builtin_amdgcn_mfma_f32_16x16x32_bf16(af[i][1], bf[j][1], acc[i][j], 0, 0, 0);
            }
        __builtin_amdgcn_s_setprio(0);
        __builtin_amdgcn_s_barrier();
        // ---- P1: read B n-hi ; stage A-half1(t+1)
        #pragma unroll
        for (int j = 2; j < 4; j++) { bf[j][0] = LDB_(j, ck0); bf[j][1] = LDB_(j, ck1); }
        if (t + 1 < NK) STG(nb, 0, 1, t + 1);
        __builtin_amdgcn_s_barrier();
        __builtin_amdgcn_s_setprio(1);
        #pragma unroll
        for (int i = 0; i < 4; i++)
            #pragma unroll
            for (int j = 2; j < 4; j++) {
                acc[i][j] = __builtin_amdgcn_mfma_f32_16x16x32_bf16(af[i][0], bf[j][0], acc[i][j], 0, 0, 0);
                acc[i][j] = __builtin_amdgcn_mfma_f32_16x16x32_bf16(af[i][1], bf[j][1], acc[i][j], 0, 0, 0);
            }
        __builtin_amdgcn_s_setprio(0);
        __builtin_amdgcn_s_barrier();
        // ---- P2: read A m-hi ; stage B-half0(t+2)
        #pragma unroll
        for (int i = 0; i < 4; i++) { af[i][0] = LDA_(4 + i, ck0); af[i][1] = LDA_(4 + i, ck1); }
        if (t + 2 < NK) STG(t & 1, 1, 0, t + 2);
        __builtin_amdgcn_s_barrier();
        __builtin_amdgcn_s_setprio(1);
        #pragma unroll
        for (int i = 0; i < 4; i++)
            #pragma unroll
            for (int j = 0; j < 2; j++) {
                acc[4 + i][j] = __builtin_amdgcn_mfma_f32_16x16x32_bf16(af[i][0], bf[j][0], acc[4 + i][j], 0, 0, 0);
                acc[4 + i][j] = __builtin_amdgcn_mfma_f32_16x16x32_bf16(af[i][1], bf[j][1], acc[4 + i][j], 0, 0, 0);
            }
        __builtin_amdgcn_s_setprio(0);
        __builtin_amdgcn_s_barrier();
        // ---- P3: stage B-half1(t+2) ; counted vmcnt (keeps B(t+2) in flight)
        if (t + 2 < NK) STG(t & 1, 1, 1, t + 2);
        __builtin_amdgcn_s_barrier();
        __builtin_amdgcn_s_setprio(1);
        #pragma unroll
        for (int i = 0; i < 4; i++)
            #pragma unroll
            for (int j = 2; j < 4; j++) {
                acc[4 + i][j] = __builtin_amdgcn_mfma_f32_16x16x32_bf16(af[i][0], bf[j][0], acc[4 + i][j], 0, 0, 0);
                acc[4 + i][j] = __builtin_amdgcn_mfma_f32_16x16x32_bf16(af[i][1], bf[j][1], acc[4 + i][j], 0, 0, 0);
            }
        __builtin_amdgcn_s_setprio(0);
        if (t + 2 < NK) { asm volatile("s_waitcnt vmcnt(4)" ::: "memory"); }
        else            { asm volatile("s_waitcnt vmcnt(0)" ::: "memory"); }
        __builtin_amdgcn_s_barrier();
    }
#undef STG
#undef LDA_
#undef LDB_
}

// ---------------------------------------------------------------------------
// eps/upd: round-0 verified kernels (128^2 core, 4 blocks/CU)
// Epilogue staging map (32 rows x 128 cols bf16 per pass, 8KB in smem[0..4095]):
//   slot row  = wm*16 + q*4 + r  (global row = m0 + (row>>4)*64 + mi*16 + (row&15))
//   col chunk rotation: slot_chunk = (chunk + 4*((row>>2)&3)) & 15
// ---------------------------------------------------------------------------

// eps_l = lower - b - mu_l @ W^T. If pc_accum==null: write eps bf16; else
// skip the write, accumulate sum(eps^2) into *pc_accum.
__global__ __launch_bounds__(256, 4) void eps_gemm_k(
        const u16* __restrict__ sbf, const u16* __restrict__ Wbf,
        const u16* __restrict__ xbf, const float* __restrict__ b_stack,
        u16* __restrict__ epsb, float* __restrict__ pc_accum) {
    __shared__ __align__(16) u16 smem[16384];
    const int z = blockIdx.z;
    const int m0 = blockIdx.y * 128, n0 = blockIdx.x * 128;
    floatx4 acc[4][4];
    gemm_core(sbf + (size_t)z * SM, Wbf + (size_t)z * WM, m0, n0, acc, smem);
    const u16* lower = (z == 0) ? xbf : (sbf + (size_t)(z - 1) * SM);
    const float* bias = b_stack + z * D_DIM;
    u16* eo = epsb + (size_t)z * SM;
    const int tid = threadIdx.x, lane = tid & 63, wave = tid >> 6;
    const int wm = wave >> 1, wn = wave & 1, q = lane >> 4, lr = lane & 15;
    float sq = 0.f;
    #pragma unroll
    for (int mi = 0; mi < 4; mi++) {
        __syncthreads();
        #pragma unroll
        for (int ni = 0; ni < 4; ni++) {
            const int col = wn * 64 + ni * 16 + lr;
            const float bc = bias[n0 + col];
            #pragma unroll
            for (int r = 0; r < 4; r++) {
                const int row = wm * 16 + q * 4 + r;
                const int scn = ((col >> 3) + ((row >> 2) & 3) * 4) & 15;
                smem[row * 128 + scn * 8 + (col & 7)] = f2b(acc[mi][ni][r] + bc);
            }
        }
        __syncthreads();
        #pragma unroll
        for (int h = 0; h < 2; h++) {
            const int c = tid + h * 256;
            const int lrow = c >> 4, ch = c & 15;
            const int scn = (ch + ((lrow >> 2) & 3) * 4) & 15;
            const int grow = m0 + (lrow >> 4) * 64 + mi * 16 + (lrow & 15);
            const size_t gidx = (size_t)grow * D_DIM + n0 + ch * 8;
            bf16x8 st = *(const bf16x8*)&smem[lrow * 128 + scn * 8];
            bf16x8 lo = *(const bf16x8*)(lower + gidx);
            float e[8];
            #pragma unroll
            for (int i = 0; i < 8; i++) e[i] = (float)lo[i] - (float)st[i];
            if (pc_accum) {
                #pragma unroll
                for (int i = 0; i < 8; i++) sq += e[i] * e[i];
            } else {
                uint4 ov;
                ov.x = pk2(e[0], e[1]); ov.y = pk2(e[2], e[3]);
                ov.z = pk2(e[4], e[5]); ov.w = pk2(e[6], e[7]);
                *(uint4*)(eo + gidx) = ov;
            }
        }
    }
    if (pc_accum) {
        #pragma unroll
        for (int off = 1; off < 64; off <<= 1) sq += __shfl_xor(sq, off, 64);
        __shared__ float ls[4];
        if (lane == 0) ls[wave] = sq;
        __syncthreads();
        if (tid == 0) atomicAdd(pc_accum, ls[0] + ls[1] + ls[2] + ls[3]);
    }
}

// s_l += LR*(eps_l @ W) - LR*eps_{l+1};  states live as bf16 only
__global__ __launch_bounds__(256, 4) void upd_gemm_k(
        const u16* __restrict__ epsb, const u16* __restrict__ WTbf,
        u16* __restrict__ sbf) {
    __shared__ __align__(16) u16 smem[16384];
    const int z = blockIdx.z;
    const int m0 = blockIdx.y * 128, n0 = blockIdx.x * 128;
    floatx4 acc[4][4];
    gemm_core(epsb + (size_t)z * SM, WTbf + (size_t)z * WM, m0, n0, acc, smem);
    u16* Sb = sbf + (size_t)z * SM;
    const bool hn = (z < 3);
    const u16* en = epsb + (size_t)(hn ? (z + 1) : z) * SM;
    const int tid = threadIdx.x, lane = tid & 63, wave = tid >> 6;
    const int wm = wave >> 1, wn = wave & 1, q = lane >> 4, lr = lane & 15;
    #pragma unroll
    for (int mi = 0; mi < 4; mi++) {
        __syncthreads();
        #pragma unroll
        for (int ni = 0; ni < 4; ni++) {
            const int col = wn * 64 + ni * 16 + lr;
            #pragma unroll
            for (int r = 0; r < 4; r++) {
                const int row = wm * 16 + q * 4 + r;
                const int scn = ((col >> 3) + ((row >> 2) & 3) * 4) & 15;
                smem[row * 128 + scn * 8 + (col & 7)] = f2b(LRS * acc[mi][ni][r]);
            }
        }
        __syncthreads();
        #pragma unroll
        for (int h = 0; h < 2; h++) {
            const int c = tid + h * 256;
            const int lrow = c >> 4, ch = c & 15;
            const int scn = (ch + ((lrow >> 2) & 3) * 4) & 15;
            const int grow = m0 + (lrow >> 4) * 64 + mi * 16 + (lrow & 15);
            const size_t gidx = (size_t)grow * D_DIM + n0 + ch * 8;
            bf16x8 st = *(const bf16x8*)&smem[lrow * 128 + scn * 8];
            bf16x8 S8 = *(const bf16x8*)(Sb + gidx);
            float v[8];
            #pragma unroll
            for (int i = 0; i < 8; i++) v[i] = (float)S8[i] + (float)st[i];
            if (hn) {
                bf16x8 e8 = *(const bf16x8*)(en + gidx);
                #pragma unroll
                for (int i = 0; i < 8; i++) v[i] -= LRS * (float)e8[i];
            }
            uint4 ov;
            ov.x = pk2(v[0], v[1]); ov.y = pk2(v[2], v[3]);
            ov.z = pk2(v[4], v[5]); ov.w = pk2(v[6], v[7]);
            *(uint4*)(Sb + gidx) = ov;
        }
    }
}

// logits tile + fused online-softmax partials + target-logit capture
// 256^2 8-phase core; grid: x = m-tile (fastest) so co-resident blocks share B
__global__ __launch_bounds__(512, 2) void logits_k(
        const u16* __restrict__ s4bf, const u16* __restrict__ oWb,
        const float* __restrict__ out_b, const int* __restrict__ targets,
        float* __restrict__ part_m, float* __restrict__ part_s,
        float* __restrict__ tlog) {
    __shared__ __align__(16) u16 smem[65536];
    const int m0 = blockIdx.x * 256, n0 = blockIdx.y * 256;
    floatx4 acc[8][4];
    gemm256(s4bf, oWb, m0, n0, acc, smem);
    const int tid = threadIdx.x, lane = tid & 63, wave = tid >> 6;
    const int wm = wave >> 2, wn = wave & 3, q = lane >> 4, lr = lane & 15;
    float* redm = (float*)smem;        // [256][4]
    float* reds = redm + 1024;
    float ob[4];
    #pragma unroll
    for (int ni = 0; ni < 4; ++ni) ob[ni] = out_b[n0 + wn * 64 + ni * 16 + lr];
    __syncthreads();
    #pragma unroll
    for (int mi = 0; mi < 8; ++mi) {
        #pragma unroll
        for (int r = 0; r < 4; ++r) {
            const int rrow = wm * 128 + mi * 16 + q * 4 + r;
            const int grow = m0 + rrow;
            float l[4];
            #pragma unroll
            for (int ni = 0; ni < 4; ni++) l[ni] = acc[mi][ni][r] + ob[ni];
            if ((grow & 511) != 511) {             // valid row (s < 511)
                const int tg = targets[grow + 1];
                #pragma unroll
                for (int ni = 0; ni < 4; ni++) {
                    const int gcol = n0 + wn * 64 + ni * 16 + lr;
                    if (tg == gcol) tlog[grow] = l[ni];
                }
            }
            float mx = fmaxf(fmaxf(l[0], l[1]), fmaxf(l[2], l[3]));
            #pragma unroll
            for (int off = 1; off < 16; off <<= 1)
                mx = fmaxf(mx, __shfl_xor(mx, off, 64));
            float sm = __expf(l[0] - mx) + __expf(l[1] - mx) +
                       __expf(l[2] - mx) + __expf(l[3] - mx);
            #pragma unroll
            for (int off = 1; off < 16; off <<= 1)
                sm += __shfl_xor(sm, off, 64);
            if (lr == 0) { redm[rrow * 4 + wn] = mx; reds[rrow * 4 + wn] = sm; }
        }
    }
    __syncthreads();
    if (tid < 256) {
        float ma = redm[tid * 4], mb = redm[tid * 4 + 1];
        float mc = redm[tid * 4 + 2], md = redm[tid * 4 + 3];
        float M = fmaxf(fmaxf(ma, mb), fmaxf(mc, md));
        float S = reds[tid * 4] * __expf(ma - M) + reds[tid * 4 + 1] * __expf(mb - M)
                + reds[tid * 4 + 2] * __expf(mc - M) + reds[tid * 4 + 3] * __expf(md - M);
        part_m[(size_t)blockIdx.y * M_ROWS + m0 + tid] = M;
        part_s[(size_t)blockIdx.y * M_ROWS + m0 + tid] = S;
    }
}

__global__ void gather_k(const int* __restrict__ ids,
                         const float* __restrict__ emb,
                         u16* __restrict__ xbf) {
    const int row = blockIdx.x;
    const int c = threadIdx.x * 4;
    float4 v = *(const float4*)(emb + (size_t)ids[row] * D_DIM + c);
    uint2 o; o.x = pk2(v.x, v.y); o.y = pk2(v.z, v.w);
    *(uint2*)(xbf + (size_t)row * D_DIM + c) = o;
}

__global__ void conv_w_k(const float* __restrict__ W,
                         u16* __restrict__ Wbf, u16* __restrict__ WTbf) {
    __shared__ float t[32][33];
    const int z = blockIdx.z;
    const int i = blockIdx.y * 32 + threadIdx.y;
    const int j = blockIdx.x * 32 + threadIdx.x;
    const float v = W[(size_t)z * WM + (size_t)i * D_DIM + j];
    Wbf[(size_t)z * WM + (size_t)i * D_DIM + j] = f2b(v);
    t[threadIdx.y][threadIdx.x] = v;
    __syncthreads();
    const int jo = blockIdx.x * 32 + threadIdx.y;
    const int io = blockIdx.y * 32 + threadIdx.x;
    WTbf[(size_t)z * WM + (size_t)jo * D_DIM + io] = f2b(t[threadIdx.x][threadIdx.y]);
}

__global__ void conv_outw_k(const float* __restrict__ oW, u16* __restrict__ oWb) {
    const size_t i = ((size_t)blockIdx.x * 256 + threadIdx.x) * 4;
    float4 v = *(const float4*)(oW + i);
    uint2 o; o.x = pk2(v.x, v.y); o.y = pk2(v.z, v.w);
    *(uint2*)(oWb + i) = o;
}

__global__ void init_states_k(const float* __restrict__ si,
                              u16* __restrict__ sbf) {
    const size_t i = ((size_t)blockIdx.x * 256 + threadIdx.x) * 4;
    float4 v = *(const float4*)(si + i);
    uint2 o; o.x = pk2(v.x, v.y); o.y = pk2(v.z, v.w);
    *(uint2*)(sbf + i) = o;
}

__global__ void ce_reduce_k(const float* __restrict__ part_m,
                            const float* __restrict__ part_s,
                            const float* __restrict__ tlog,
                            float* __restrict__ ce_sum) {
    const int row = blockIdx.x;
    if ((row & 511) == 511) return;
    const int tid = threadIdx.x;
    const int NT = NTV;  // 125
    float m = -3.0e38f;
    for (int nt = tid; nt < NT; nt += 256)
        m = fmaxf(m, part_m[(size_t)nt * M_ROWS + row]);
    #pragma unroll
    for (int off = 1; off < 64; off <<= 1) m = fmaxf(m, __shfl_xor(m, off, 64));
    __shared__ float sm[4], ss[4];
    if ((tid & 63) == 0) sm[tid >> 6] = m;
    __syncthreads();
    m = fmaxf(fmaxf(sm[0], sm[1]), fmaxf(sm[2], sm[3]));
    float s = 0.f;
    for (int nt = tid; nt < NT; nt += 256)
        s += part_s[(size_t)nt * M_ROWS + row] *
             __expf(part_m[(size_t)nt * M_ROWS + row] - m);
    #pragma unroll
    for (int off = 1; off < 64; off <<= 1) s += __shfl_xor(s, off, 64);
    if ((tid & 63) == 0) ss[tid >> 6] = s;
    __syncthreads();
    if (tid == 0) {
        float loss = m + __logf(ss[0] + ss[1] + ss[2] + ss[3]) - tlog[row];
        atomicAdd(ce_sum, loss);
    }
}

__global__ void finalize_k(const float* __restrict__ scal, float* __restrict__ out) {
    out[0] = scal[0] / 4088.0f;
    out[1] = scal[1] / (float)(4 * SM);
}

extern "C" void kernel_launch(void* const* d_in, const int* in_sizes, int n_in,
                              void* d_out, int out_size, void* d_ws, size_t ws_size,
                              hipStream_t stream) {
    (void)in_sizes; (void)n_in; (void)out_size; (void)ws_size;
    const int*   ids = (const int*)d_in[0];
    const int*   tgt = (const int*)d_in[1];
    const float* emb = (const float*)d_in[2];
    const float* W   = (const float*)d_in[3];
    const float* bs  = (const float*)d_in[4];
    const float* oW  = (const float*)d_in[5];
    const float* ob  = (const float*)d_in[6];
    const float* si  = (const float*)d_in[7];

    char* ws = (char*)d_ws;
    u16*   sbf    = (u16*)  (ws + 0);             // 33,554,432 B
    u16*   epsb   = (u16*)  (ws + 33554432);      // 33,554,432 B
    u16*   xbf    = (u16*)  (ws + 67108864);      //  8,388,608 B
    u16*   Wbf    = (u16*)  (ws + 75497472);      //  8,388,608 B
    u16*   WTbf   = (u16*)  (ws + 83886080);      //  8,388,608 B
    u16*   oWb    = (u16*)  (ws + 92274688);      // 65,536,000 B
    float* part_m = (float*)(ws + 157810688);     //  4,096,000 B (125 used)
    float* part_s = (float*)(ws + 161906688);     //  4,096,000 B
    float* tlog   = (float*)(ws + 166002688);     //     16,384 B
    float* scal   = (float*)(ws + 166019072);     //        256 B

    hipMemsetAsync(scal, 0, 256, stream);
    gather_k<<<M_ROWS, 256, 0, stream>>>(ids, emb, xbf);
    conv_w_k<<<dim3(32, 32, 4), dim3(32, 32), 0, stream>>>(W, Wbf, WTbf);
    conv_outw_k<<<(V_DIM * D_DIM) / 1024, 256, 0, stream>>>(oW, oWb);
    init_states_k<<<(4 * (int)SM) / 1024, 256, 0, stream>>>(si, sbf);

    for (int step = 0; step < STEPS; ++step) {
        eps_gemm_k<<<dim3(8, 32, 4), 256, 0, stream>>>(sbf, Wbf, xbf, bs, epsb,
                                                       nullptr);
        upd_gemm_k<<<dim3(8, 32, 4), 256, 0, stream>>>(epsb, WTbf, sbf);
    }
    // final eps pass: no eps write, accumulate sum(eps^2) directly
    eps_gemm_k<<<dim3(8, 32, 4), 256, 0, stream>>>(sbf, Wbf, xbf, bs, epsb,
                                                   scal + 1);
    logits_k<<<dim3(16, NTV), 512, 0, stream>>>(sbf + 3 * SM, oWb, ob, tgt,
                                                part_m, part_s, tlog);
    ce_reduce_k<<<M_ROWS, 256, 0, stream>>>(part_m, part_s, tlog, scal);
    finalize_k<<<1, 1, 0, stream>>>(scal, (float*)d_out);
}